// Round 9
// baseline (76.302 us; speedup 1.0000x reference)
//
#include <hip/hip_runtime.h>

// Involution1d fused v2: B=16, CH=256, DIM=4096, G=16, K=7, PAD=3,
// hid=64, K*G=112.  setup (f16 weights) -> fused (panel-streamed x -> MFMA
// kerngen -> kern in LDS -> involution with global-f32 x taps -> out).
// LDS ~63 KiB -> 2 blocks/CU; grid 512 = whole grid co-resident.
#define BB   16
#define CHN  256
#define DIMN 4096
#define KK   7
#define PADK 3
#define HID  64
#define KGN  112
#define TLC  128       // columns (locations) per block tile
#define NPAN 8         // channel panels
#define PCH  32        // channels per panel (= one MFMA K-step)
#define XSTD 66        // panel row stride in u32 (= 132 halves)
#define HSTH 138       // hs row stride in halves
#define KSTD 132       // ks row stride in u32
#define BN_EPS 1e-5f

typedef __fp16 half2_t __attribute__((ext_vector_type(2)));
typedef __fp16 half8   __attribute__((ext_vector_type(8)));
typedef float  f32x4   __attribute__((ext_vector_type(4)));

union U32H2 { unsigned int u; half2_t h; };

static __device__ __forceinline__ unsigned int packf(float a, float b) {
    U32H2 t; t.h = __builtin_amdgcn_cvt_pkrtz(a, b); return t.u;
}
static __device__ __forceinline__ half2_t ash2(unsigned int u) { U32H2 t; t.u = u; return t.h; }
static __device__ __forceinline__ __fp16 u16h(unsigned short u) {
    return __builtin_bit_cast(__fp16, u);
}
static __device__ __forceinline__ unsigned short hu16(__fp16 h) {
    return __builtin_bit_cast(unsigned short, h);
}

// ---------------------------------------------------------------------------
// Convert w1 [64][256] and w2 [112][64] to f16 (layout unchanged); BN affine.
__global__ __launch_bounds__(256) void setup_k(
    const float* __restrict__ w1, const float* __restrict__ w2,
    const float* __restrict__ bn_gamma, const float* __restrict__ bn_beta,
    const float* __restrict__ bn_mean,  const float* __restrict__ bn_var,
    __fp16* __restrict__ w1f, __fp16* __restrict__ w2f,
    float* __restrict__ scb, float* __restrict__ shb) {
    int t = blockIdx.x * 256 + threadIdx.x;   // grid covers 16384
    if (t < HID * CHN) w1f[t] = (__fp16)w1[t];
    if (t < KGN * HID) w2f[t] = (__fp16)w2[t];
    if (t < HID) {
        float s = bn_gamma[t] * rsqrtf(bn_var[t] + BN_EPS);
        scb[t] = s;
        shb[t] = bn_beta[t] - bn_mean[t] * s;
    }
}

// ---------------------------------------------------------------------------
// kern extraction from row-pair-packed uint4 quads; OFF = (7g)&1.
// q[i] = ks rows-pair (rpb+i), cols col0..col0+3.
template <int OFF>
static __device__ __forceinline__ void extract_kv(const uint4 q[4], float kv[KK][4]) {
#pragma unroll
    for (int k = 0; k < KK; ++k) {
        const int kk = k + OFF;
        const int i  = kk >> 1;
        const int h  = kk & 1;
#pragma unroll
        for (int j = 0; j < 4; ++j) {
            unsigned int u = (&q[i].x)[j];
            half2_t hh = ash2(u);
            kv[k][j] = h ? (float)hh[1] : (float)hh[0];
        }
    }
}

// ---------------------------------------------------------------------------
// Fused kernel.  Block = (b, 128-col tile), 8 waves, 2 blocks/CU.
// Phases 1/2: wave w owns cols [16w,16w+16).
// Involution: wave w owns g in {2w, 2w+1}; lane -> col quad (l&31), ch parity (l>>5).
// Fragment maps (16x16x32): A[m][k]: m=lane&15, k=8*((lane>>4)&3)+j;
// B[k][n]: n=lane&15; D[m][n]: n=lane&15, m=4*((lane>>4)&3)+reg.
__global__ __launch_bounds__(512, 4) void fused_k(
    const float* __restrict__ x,
    const __fp16* __restrict__ w1f,
    const float* __restrict__ b1,
    const float* __restrict__ scb, const float* __restrict__ shb,
    const __fp16* __restrict__ w2f,
    const float* __restrict__ b2,
    float* __restrict__ out) {
    __shared__ unsigned int   xs[2][PCH * XSTD];   // 2 x 8448 B
    __shared__ unsigned short hs[HID * HSTH];      // 17664 B
    __shared__ unsigned int   ks[56 * KSTD];       // 29568 B  (total 62.6 KiB)

    const int t    = threadIdx.x;          // 0..511
    const int lane = t & 63;
    const int w    = t >> 6;               // wave 0..7
    const int lr   = t & 15;
    const int lg   = (t >> 4) & 3;
    const int b    = blockIdx.x >> 5;
    const int l0   = (blockIdx.x & 31) * TLC;
    const int colL = 16 * w + lr;          // wave's column (0..127)

    const unsigned short* xs16[2] = {
        (const unsigned short*)xs[0], (const unsigned short*)xs[1] };

    // staging assignment: colq = col quad, chl = row within 16-row half-panel
    const int colq = t & 31;
    const int chl  = t >> 5;               // 0..15
    const float* xg = x + ((size_t)b * CHN + chl) * DIMN + l0 + 4 * colq;

    // ---- prologue: stage panel 0 (rows chl, chl+16)
    float4 pre[2];
#pragma unroll
    for (int i = 0; i < 2; ++i)
        pre[i] = *(const float4*)(xg + (size_t)(16 * i) * DIMN);
#pragma unroll
    for (int i = 0; i < 2; ++i) {
        uint2 v;
        v.x = packf(pre[i].x, pre[i].y);
        v.y = packf(pre[i].z, pre[i].w);
        *(uint2*)&xs[0][(chl + 16 * i) * XSTD + 2 * colq] = v;
    }
    __syncthreads();

    // ---- Phase 1: h = w1 . x  (4 o-frags x 8 panels) ----
    f32x4 acc[4];
#pragma unroll
    for (int of = 0; of < 4; ++of) acc[of] = (f32x4){0.f, 0.f, 0.f, 0.f};

    for (int p = 0; p < NPAN; ++p) {
        if (p + 1 < NPAN) {
#pragma unroll
            for (int i = 0; i < 2; ++i)
                pre[i] = *(const float4*)(xg + (size_t)(32 * (p + 1) + 16 * i) * DIMN);
        }
        const unsigned short* xb = xs16[p & 1];
        half8 bf;
#pragma unroll
        for (int j = 0; j < 8; ++j)
            bf[j] = u16h(xb[(8 * lg + j) * (2 * XSTD) + colL]);
#pragma unroll
        for (int of = 0; of < 4; ++of) {
            half8 af = *(const half8*)(w1f + (16 * of + lr) * CHN + PCH * p + 8 * lg);
            acc[of] = __builtin_amdgcn_mfma_f32_16x16x32_f16(af, bf, acc[of], 0, 0, 0);
        }
        if (p + 1 < NPAN) {
            __syncthreads();
#pragma unroll
            for (int i = 0; i < 2; ++i) {
                uint2 v;
                v.x = packf(pre[i].x, pre[i].y);
                v.y = packf(pre[i].z, pre[i].w);
                *(uint2*)&xs[(p + 1) & 1][(chl + 16 * i) * XSTD + 2 * colq] = v;
            }
            __syncthreads();
        }
    }

    // ---- bias + relu + BN; h -> hs (wave-private cols, same-wave consumer)
#pragma unroll
    for (int of = 0; of < 4; ++of) {
#pragma unroll
        for (int r = 0; r < 4; ++r) {
            const int o = 16 * of + 4 * lg + r;
            float hv = fmaxf(acc[of][r] + b1[o], 0.f) * scb[o] + shb[o];
            hs[o * HSTH + colL] = hu16((__fp16)hv);
        }
    }

    // ---- Phase 2: kern = w2 . h  (7 r-frags x 2 K-steps) ----
    f32x4 acc2[7];
#pragma unroll
    for (int rf = 0; rf < 7; ++rf) acc2[rf] = (f32x4){0.f, 0.f, 0.f, 0.f};

#pragma unroll
    for (int kx = 0; kx < 2; ++kx) {
        half8 bf;
#pragma unroll
        for (int j = 0; j < 8; ++j)
            bf[j] = u16h(hs[(32 * kx + 8 * lg + j) * HSTH + colL]);
#pragma unroll
        for (int rf = 0; rf < 7; ++rf) {
            half8 af = *(const half8*)(w2f + (16 * rf + lr) * HID + 32 * kx + 8 * lg);
            acc2[rf] = __builtin_amdgcn_mfma_f32_16x16x32_f16(af, bf, acc2[rf], 0, 0, 0);
        }
    }

    // ---- bias + row-pair pack -> ks LDS
#pragma unroll
    for (int rf = 0; rf < 7; ++rf) {
#pragma unroll
        for (int p = 0; p < 2; ++p) {
            const int r0 = 16 * rf + 4 * lg + 2 * p;
            float k0 = acc2[rf][2 * p + 0] + b2[r0 + 0];
            float k1 = acc2[rf][2 * p + 1] + b2[r0 + 1];
            ks[(r0 >> 1) * KSTD + colL] = packf(k0, k1);
        }
    }
    __syncthreads();

    // ---- Involution: wave w -> groups {2w, 2w+1}; x taps from global f32 ----
    const int q4   = lane & 31;
    const int hi   = lane >> 5;
    const int col0 = l0 + 4 * q4;

#pragma unroll
    for (int gi = 0; gi < 2; ++gi) {
        const int g   = 2 * w + gi;            // parity = gi
        const int rpb = (7 * g) >> 1;
        uint4 qq[4];
#pragma unroll
        for (int ii = 0; ii < 4; ++ii)
            qq[ii] = *(const uint4*)(ks + (rpb + ii) * KSTD + 4 * q4);
        float kv[KK][4];
        if (gi == 0) extract_kv<0>(qq, kv);
        else         extract_kv<1>(qq, kv);

#pragma unroll 4
        for (int i2 = 0; i2 < 8; ++i2) {
            const int ch = 32 * w + 16 * gi + 2 * i2 + hi;
            const float* xrow = x + ((size_t)b * CHN + ch) * DIMN;
            float4 fa = *(const float4*)(xrow + (col0 > 0 ? col0 - 4 : 0));
            float4 fb = *(const float4*)(xrow + col0);
            float4 fc = *(const float4*)(xrow + (col0 + 4 < DIMN ? col0 + 4 : DIMN - 4));

            float xr[10] = { fa.y, fa.z, fa.w, fb.x, fb.y, fb.z, fb.w, fc.x, fc.y, fc.z };
            if (col0 == 0)        { xr[0] = 0.f; xr[1] = 0.f; xr[2] = 0.f; }
            if (col0 == DIMN - 4) { xr[7] = 0.f; xr[8] = 0.f; xr[9] = 0.f; }

            float o0 = 0.f, o1 = 0.f, o2 = 0.f, o3 = 0.f;
#pragma unroll
            for (int k = 0; k < KK; ++k) {
                o0 = fmaf(kv[k][0], xr[k + 0], o0);
                o1 = fmaf(kv[k][1], xr[k + 1], o1);
                o2 = fmaf(kv[k][2], xr[k + 2], o2);
                o3 = fmaf(kv[k][3], xr[k + 3], o3);
            }
            *(float4*)(out + ((size_t)b * CHN + ch) * DIMN + col0) =
                make_float4(o0, o1, o2, o3);
        }
    }
}

// ---------------------------------------------------------------------------
extern "C" void kernel_launch(void* const* d_in, const int* in_sizes, int n_in,
                              void* d_out, int out_size, void* d_ws, size_t ws_size,
                              hipStream_t stream) {
    (void)in_sizes; (void)n_in; (void)out_size; (void)ws_size;

    const float* x        = (const float*)d_in[0];
    const float* w1       = (const float*)d_in[1];
    const float* b1       = (const float*)d_in[2];
    const float* bn_gamma = (const float*)d_in[3];
    const float* bn_beta  = (const float*)d_in[4];
    const float* bn_mean  = (const float*)d_in[5];
    const float* bn_var   = (const float*)d_in[6];
    const float* w2       = (const float*)d_in[7];
    const float* b2       = (const float*)d_in[8];
    float*       out      = (float*)d_out;

    __fp16* w1f = (__fp16*)d_ws;                 // 16384 f16
    __fp16* w2f = w1f + HID * CHN;               // 7168 f16
    float*  scb = (float*)(w2f + KGN * HID);     // 64
    float*  shb = scb + HID;                     // 64

    setup_k<<<(HID * CHN + 255) / 256, 256, 0, stream>>>(
        w1, w2, bn_gamma, bn_beta, bn_mean, bn_var, w1f, w2f, scb, shb);
    fused_k<<<BB * (DIMN / TLC), 512, 0, stream>>>(
        x, w1f, b1, scb, shb, w2f, b2, out);
}

// Round 10
// 64.480 us; speedup vs baseline: 1.1833x; 1.1833x over previous
//
#include <hip/hip_runtime.h>

// Involution1d fused v3: B=16, CH=256, DIM=4096, G=16, K=7, PAD=3,
// hid=64, K*G=112.  setup (f16 weights) -> fused (panel-streamed x -> MFMA
// kerngen -> kern in LDS -> involution with global-f32 x taps -> out).
// LDS ~63 KiB, launch_bounds(512,2): 2 blocks/CU, VGPR cap 128 (no spill).
#define BB   16
#define CHN  256
#define DIMN 4096
#define KK   7
#define PADK 3
#define HID  64
#define KGN  112
#define TLC  128       // columns (locations) per block tile
#define NPAN 8         // channel panels
#define PCH  32        // channels per panel (= one MFMA K-step)
#define XSTD 66        // panel row stride in u32 (= 132 halves)
#define HSTH 138       // hs row stride in halves
#define KSTD 132       // ks row stride in u32
#define BN_EPS 1e-5f

typedef __fp16 half2_t __attribute__((ext_vector_type(2)));
typedef __fp16 half8   __attribute__((ext_vector_type(8)));
typedef float  f32x4   __attribute__((ext_vector_type(4)));

union U32H2 { unsigned int u; half2_t h; };

static __device__ __forceinline__ unsigned int packf(float a, float b) {
    U32H2 t; t.h = __builtin_amdgcn_cvt_pkrtz(a, b); return t.u;
}
static __device__ __forceinline__ half2_t ash2(unsigned int u) { U32H2 t; t.u = u; return t.h; }
static __device__ __forceinline__ __fp16 u16h(unsigned short u) {
    return __builtin_bit_cast(__fp16, u);
}
static __device__ __forceinline__ unsigned short hu16(__fp16 h) {
    return __builtin_bit_cast(unsigned short, h);
}

// ---------------------------------------------------------------------------
// Convert w1 [64][256] and w2 [112][64] to f16 (layout unchanged); BN affine.
__global__ __launch_bounds__(256) void setup_k(
    const float* __restrict__ w1, const float* __restrict__ w2,
    const float* __restrict__ bn_gamma, const float* __restrict__ bn_beta,
    const float* __restrict__ bn_mean,  const float* __restrict__ bn_var,
    __fp16* __restrict__ w1f, __fp16* __restrict__ w2f,
    float* __restrict__ scb, float* __restrict__ shb) {
    int t = blockIdx.x * 256 + threadIdx.x;   // grid covers 16384
    if (t < HID * CHN) w1f[t] = (__fp16)w1[t];
    if (t < KGN * HID) w2f[t] = (__fp16)w2[t];
    if (t < HID) {
        float s = bn_gamma[t] * rsqrtf(bn_var[t] + BN_EPS);
        scb[t] = s;
        shb[t] = bn_beta[t] - bn_mean[t] * s;
    }
}

// ---------------------------------------------------------------------------
// kern extraction from row-pair-packed uint4 quads; OFF = (7g)&1.
// q[i] = ks rows-pair (rpb+i), cols col0..col0+3.
template <int OFF>
static __device__ __forceinline__ void extract_kv(const uint4 q[4], float kv[KK][4]) {
#pragma unroll
    for (int k = 0; k < KK; ++k) {
        const int kk = k + OFF;
        const int i  = kk >> 1;
        const int h  = kk & 1;
#pragma unroll
        for (int j = 0; j < 4; ++j) {
            unsigned int u = (&q[i].x)[j];
            half2_t hh = ash2(u);
            kv[k][j] = h ? (float)hh[1] : (float)hh[0];
        }
    }
}

// ---------------------------------------------------------------------------
// Fused kernel.  Block = (b, 128-col tile), 8 waves, 2 blocks/CU.
// Phases 1/2: wave w owns cols [16w,16w+16).
// Involution: wave w owns g in {2w, 2w+1}; lane -> col quad (l&31), ch parity (l>>5).
// Fragment maps (16x16x32): A[m][k]: m=lane&15, k=8*((lane>>4)&3)+j;
// B[k][n]: n=lane&15; D[m][n]: n=lane&15, m=4*((lane>>4)&3)+reg.
__global__ __launch_bounds__(512, 2) void fused_k(
    const float* __restrict__ x,
    const __fp16* __restrict__ w1f,
    const float* __restrict__ b1,
    const float* __restrict__ scb, const float* __restrict__ shb,
    const __fp16* __restrict__ w2f,
    const float* __restrict__ b2,
    float* __restrict__ out) {
    __shared__ unsigned int   xs[2][PCH * XSTD];   // 2 x 8448 B
    __shared__ unsigned short hs[HID * HSTH];      // 17664 B
    __shared__ unsigned int   ks[56 * KSTD];       // 29568 B  (total 62.6 KiB)

    const int t    = threadIdx.x;          // 0..511
    const int lane = t & 63;
    const int w    = t >> 6;               // wave 0..7
    const int lr   = t & 15;
    const int lg   = (t >> 4) & 3;
    const int b    = blockIdx.x >> 5;
    const int l0   = (blockIdx.x & 31) * TLC;
    const int colL = 16 * w + lr;          // wave's column (0..127)

    const unsigned short* xs16[2] = {
        (const unsigned short*)xs[0], (const unsigned short*)xs[1] };

    // staging assignment: colq = col quad, chl = row within 16-row half-panel
    const int colq = t & 31;
    const int chl  = t >> 5;               // 0..15
    const float* xg = x + ((size_t)b * CHN + chl) * DIMN + l0 + 4 * colq;

    // ---- prologue: stage panel 0 (rows chl, chl+16)
    float4 pre[2];
#pragma unroll
    for (int i = 0; i < 2; ++i)
        pre[i] = *(const float4*)(xg + (size_t)(16 * i) * DIMN);
#pragma unroll
    for (int i = 0; i < 2; ++i) {
        uint2 v;
        v.x = packf(pre[i].x, pre[i].y);
        v.y = packf(pre[i].z, pre[i].w);
        *(uint2*)&xs[0][(chl + 16 * i) * XSTD + 2 * colq] = v;
    }
    __syncthreads();

    // ---- Phase 1: h = w1 . x  (4 o-frags x 8 panels) ----
    f32x4 acc[4];
#pragma unroll
    for (int of = 0; of < 4; ++of) acc[of] = (f32x4){0.f, 0.f, 0.f, 0.f};

    for (int p = 0; p < NPAN; ++p) {
        if (p + 1 < NPAN) {
#pragma unroll
            for (int i = 0; i < 2; ++i)
                pre[i] = *(const float4*)(xg + (size_t)(32 * (p + 1) + 16 * i) * DIMN);
        }
        const unsigned short* xb = xs16[p & 1];
        half8 bf;
#pragma unroll
        for (int j = 0; j < 8; ++j)
            bf[j] = u16h(xb[(8 * lg + j) * (2 * XSTD) + colL]);
#pragma unroll
        for (int of = 0; of < 4; ++of) {
            half8 af = *(const half8*)(w1f + (16 * of + lr) * CHN + PCH * p + 8 * lg);
            acc[of] = __builtin_amdgcn_mfma_f32_16x16x32_f16(af, bf, acc[of], 0, 0, 0);
        }
        if (p + 1 < NPAN) {
            __syncthreads();
#pragma unroll
            for (int i = 0; i < 2; ++i) {
                uint2 v;
                v.x = packf(pre[i].x, pre[i].y);
                v.y = packf(pre[i].z, pre[i].w);
                *(uint2*)&xs[(p + 1) & 1][(chl + 16 * i) * XSTD + 2 * colq] = v;
            }
            __syncthreads();
        }
    }

    // ---- bias + relu + BN; h -> hs (wave-private cols, same-wave consumer)
#pragma unroll
    for (int of = 0; of < 4; ++of) {
#pragma unroll
        for (int r = 0; r < 4; ++r) {
            const int o = 16 * of + 4 * lg + r;
            float hv = fmaxf(acc[of][r] + b1[o], 0.f) * scb[o] + shb[o];
            hs[o * HSTH + colL] = hu16((__fp16)hv);
        }
    }

    // ---- Phase 2: kern = w2 . h  (7 r-frags x 2 K-steps) ----
    f32x4 acc2[7];
#pragma unroll
    for (int rf = 0; rf < 7; ++rf) acc2[rf] = (f32x4){0.f, 0.f, 0.f, 0.f};

#pragma unroll
    for (int kx = 0; kx < 2; ++kx) {
        half8 bf;
#pragma unroll
        for (int j = 0; j < 8; ++j)
            bf[j] = u16h(hs[(32 * kx + 8 * lg + j) * HSTH + colL]);
#pragma unroll
        for (int rf = 0; rf < 7; ++rf) {
            half8 af = *(const half8*)(w2f + (16 * rf + lr) * HID + 32 * kx + 8 * lg);
            acc2[rf] = __builtin_amdgcn_mfma_f32_16x16x32_f16(af, bf, acc2[rf], 0, 0, 0);
        }
    }

    // ---- bias + row-pair pack -> ks LDS
#pragma unroll
    for (int rf = 0; rf < 7; ++rf) {
#pragma unroll
        for (int p = 0; p < 2; ++p) {
            const int r0 = 16 * rf + 4 * lg + 2 * p;
            float k0 = acc2[rf][2 * p + 0] + b2[r0 + 0];
            float k1 = acc2[rf][2 * p + 1] + b2[r0 + 1];
            ks[(r0 >> 1) * KSTD + colL] = packf(k0, k1);
        }
    }
    __syncthreads();

    // ---- Involution: wave w -> groups {2w, 2w+1}; x taps from global f32 ----
    const int q4   = lane & 31;
    const int hi   = lane >> 5;
    const int col0 = l0 + 4 * q4;

#pragma unroll
    for (int gi = 0; gi < 2; ++gi) {
        const int g   = 2 * w + gi;            // parity = gi
        const int rpb = (7 * g) >> 1;
        uint4 qq[4];
#pragma unroll
        for (int ii = 0; ii < 4; ++ii)
            qq[ii] = *(const uint4*)(ks + (rpb + ii) * KSTD + 4 * q4);
        float kv[KK][4];
        if (gi == 0) extract_kv<0>(qq, kv);
        else         extract_kv<1>(qq, kv);

#pragma unroll 4
        for (int i2 = 0; i2 < 8; ++i2) {
            const int ch = 32 * w + 16 * gi + 2 * i2 + hi;
            const float* xrow = x + ((size_t)b * CHN + ch) * DIMN;
            float4 fa = *(const float4*)(xrow + (col0 > 0 ? col0 - 4 : 0));
            float4 fb = *(const float4*)(xrow + col0);
            float4 fc = *(const float4*)(xrow + (col0 + 4 < DIMN ? col0 + 4 : DIMN - 4));

            float xr[10] = { fa.y, fa.z, fa.w, fb.x, fb.y, fb.z, fb.w, fc.x, fc.y, fc.z };
            if (col0 == 0)        { xr[0] = 0.f; xr[1] = 0.f; xr[2] = 0.f; }
            if (col0 == DIMN - 4) { xr[7] = 0.f; xr[8] = 0.f; xr[9] = 0.f; }

            float o0 = 0.f, o1 = 0.f, o2 = 0.f, o3 = 0.f;
#pragma unroll
            for (int k = 0; k < KK; ++k) {
                o0 = fmaf(kv[k][0], xr[k + 0], o0);
                o1 = fmaf(kv[k][1], xr[k + 1], o1);
                o2 = fmaf(kv[k][2], xr[k + 2], o2);
                o3 = fmaf(kv[k][3], xr[k + 3], o3);
            }
            *(float4*)(out + ((size_t)b * CHN + ch) * DIMN + col0) =
                make_float4(o0, o1, o2, o3);
        }
    }
}

// ---------------------------------------------------------------------------
extern "C" void kernel_launch(void* const* d_in, const int* in_sizes, int n_in,
                              void* d_out, int out_size, void* d_ws, size_t ws_size,
                              hipStream_t stream) {
    (void)in_sizes; (void)n_in; (void)out_size; (void)ws_size;

    const float* x        = (const float*)d_in[0];
    const float* w1       = (const float*)d_in[1];
    const float* b1       = (const float*)d_in[2];
    const float* bn_gamma = (const float*)d_in[3];
    const float* bn_beta  = (const float*)d_in[4];
    const float* bn_mean  = (const float*)d_in[5];
    const float* bn_var   = (const float*)d_in[6];
    const float* w2       = (const float*)d_in[7];
    const float* b2       = (const float*)d_in[8];
    float*       out      = (float*)d_out;

    __fp16* w1f = (__fp16*)d_ws;                 // 16384 f16
    __fp16* w2f = w1f + HID * CHN;               // 7168 f16
    float*  scb = (float*)(w2f + KGN * HID);     // 64
    float*  shb = scb + HID;                     // 64

    setup_k<<<(HID * CHN + 255) / 256, 256, 0, stream>>>(
        w1, w2, bn_gamma, bn_beta, bn_mean, bn_var, w1f, w2f, scb, shb);
    fused_k<<<BB * (DIMN / TLC), 512, 0, stream>>>(
        x, w1f, b1, scb, shb, w2f, b2, out);
}

// Round 11
// 60.998 us; speedup vs baseline: 1.2509x; 1.0571x over previous
//
#include <hip/hip_runtime.h>

// Involution1d fused v4: B=16, CH=256, DIM=4096, G=16, K=7, PAD=3,
// hid=64, K*G=112.  setup (f16 weights) -> fused (panel-streamed x -> MFMA
// kerngen -> kern in LDS -> involution with global-f32 x taps -> out).
// 256-thread blocks, TLC=64, LDS 32.2 KiB -> 4-5 blocks/CU co-resident.
#define BB   16
#define CHN  256
#define DIMN 4096
#define KK   7
#define PADK 3
#define HID  64
#define KGN  112
#define TLC  64        // columns (locations) per block tile
#define NPAN 8         // channel panels
#define PCH  32        // channels per panel (= one MFMA K-step)
#define XSTD 33        // panel row stride in u32 (= 66 halves, odd dw)
#define HSTH 70        // hs row stride in halves (35 dw, odd)
#define KSTD 66        // ks row stride in u32 (even; 4-way on writes only)
#define BN_EPS 1e-5f

typedef __fp16 half2_t __attribute__((ext_vector_type(2)));
typedef __fp16 half8   __attribute__((ext_vector_type(8)));
typedef float  f32x4   __attribute__((ext_vector_type(4)));

union U32H2 { unsigned int u; half2_t h; };

static __device__ __forceinline__ unsigned int packf(float a, float b) {
    U32H2 t; t.h = __builtin_amdgcn_cvt_pkrtz(a, b); return t.u;
}
static __device__ __forceinline__ half2_t ash2(unsigned int u) { U32H2 t; t.u = u; return t.h; }
static __device__ __forceinline__ __fp16 u16h(unsigned short u) {
    return __builtin_bit_cast(__fp16, u);
}
static __device__ __forceinline__ unsigned short hu16(__fp16 h) {
    return __builtin_bit_cast(unsigned short, h);
}

// ---------------------------------------------------------------------------
// Convert w1 [64][256] and w2 [112][64] to f16 (layout unchanged); BN affine.
__global__ __launch_bounds__(256) void setup_k(
    const float* __restrict__ w1, const float* __restrict__ w2,
    const float* __restrict__ bn_gamma, const float* __restrict__ bn_beta,
    const float* __restrict__ bn_mean,  const float* __restrict__ bn_var,
    __fp16* __restrict__ w1f, __fp16* __restrict__ w2f,
    float* __restrict__ scb, float* __restrict__ shb) {
    int t = blockIdx.x * 256 + threadIdx.x;   // grid covers 16384
    if (t < HID * CHN) w1f[t] = (__fp16)w1[t];
    if (t < KGN * HID) w2f[t] = (__fp16)w2[t];
    if (t < HID) {
        float s = bn_gamma[t] * rsqrtf(bn_var[t] + BN_EPS);
        scb[t] = s;
        shb[t] = bn_beta[t] - bn_mean[t] * s;
    }
}

// ---------------------------------------------------------------------------
// kern extraction from row-pair-packed uint4 quads; OFF = (7g)&1.
// q[i] = ks row-pair (rpb+i), cols 4q4..4q4+3.
template <int OFF>
static __device__ __forceinline__ void extract_kv(const uint4 q[4], float kv[KK][4]) {
#pragma unroll
    for (int k = 0; k < KK; ++k) {
        const int kk = k + OFF;
        const int i  = kk >> 1;
        const int h  = kk & 1;
#pragma unroll
        for (int j = 0; j < 4; ++j) {
            unsigned int u = (&q[i].x)[j];
            half2_t hh = ash2(u);
            kv[k][j] = h ? (float)hh[1] : (float)hh[0];
        }
    }
}

// ---------------------------------------------------------------------------
// Fused kernel.  Block = (b, 64-col tile), 4 waves, 4-5 blocks/CU.
// Phases 1/2: wave w owns cols [16w,16w+16).
// Involution: wave w owns g in {4w..4w+3}; lane -> col quad (l&15), ch (l>>4).
// Fragment maps (16x16x32): A[m][k]: m=lane&15, k=8*((lane>>4)&3)+j;
// B[k][n]: n=lane&15; D[m][n]: n=lane&15, m=4*((lane>>4)&3)+reg.
__global__ __launch_bounds__(256, 4) void fused_k(
    const float* __restrict__ x,
    const __fp16* __restrict__ w1f,
    const float* __restrict__ b1,
    const float* __restrict__ scb, const float* __restrict__ shb,
    const __fp16* __restrict__ w2f,
    const float* __restrict__ b2,
    float* __restrict__ out) {
    __shared__ unsigned int   xs[2][PCH * XSTD];   // 2 x 4224 B
    __shared__ unsigned short hs[HID * HSTH];      // 8960 B
    __shared__ unsigned int   ks[56 * KSTD];       // 14784 B  (total 32.2 KiB)

    const int t    = threadIdx.x;          // 0..255
    const int lane = t & 63;
    const int w    = t >> 6;               // wave 0..3
    const int lr   = t & 15;
    const int lg   = (t >> 4) & 3;
    const int b    = blockIdx.x >> 6;
    const int l0   = (blockIdx.x & 63) * TLC;
    const int colL = 16 * w + lr;          // wave's column (0..63)

    const unsigned short* xs16[2] = {
        (const unsigned short*)xs[0], (const unsigned short*)xs[1] };

    // staging: colq = col quad (0..15), chl = row within 16-row half-panel
    const int colq = t & 15;
    const int chl  = t >> 4;               // 0..15
    const float* xg = x + ((size_t)b * CHN + chl) * DIMN + l0 + 4 * colq;

    // ---- prologue: stage panel 0 (rows chl, chl+16)
    float4 pre[2];
#pragma unroll
    for (int i = 0; i < 2; ++i)
        pre[i] = *(const float4*)(xg + (size_t)(16 * i) * DIMN);
#pragma unroll
    for (int i = 0; i < 2; ++i) {
        uint2 v;
        v.x = packf(pre[i].x, pre[i].y);
        v.y = packf(pre[i].z, pre[i].w);
        *(uint2*)&xs[0][(chl + 16 * i) * XSTD + 2 * colq] = v;
    }
    __syncthreads();

    // ---- Phase 1: h = w1 . x  (4 o-frags x 8 panels) ----
    f32x4 acc[4];
#pragma unroll
    for (int of = 0; of < 4; ++of) acc[of] = (f32x4){0.f, 0.f, 0.f, 0.f};

    for (int p = 0; p < NPAN; ++p) {
        if (p + 1 < NPAN) {
#pragma unroll
            for (int i = 0; i < 2; ++i)
                pre[i] = *(const float4*)(xg + (size_t)(32 * (p + 1) + 16 * i) * DIMN);
        }
        const unsigned short* xb = xs16[p & 1];
        half8 bf;
#pragma unroll
        for (int j = 0; j < 8; ++j)
            bf[j] = u16h(xb[(8 * lg + j) * (2 * XSTD) + colL]);
#pragma unroll
        for (int of = 0; of < 4; ++of) {
            half8 af = *(const half8*)(w1f + (16 * of + lr) * CHN + PCH * p + 8 * lg);
            acc[of] = __builtin_amdgcn_mfma_f32_16x16x32_f16(af, bf, acc[of], 0, 0, 0);
        }
        if (p + 1 < NPAN) {
            __syncthreads();
#pragma unroll
            for (int i = 0; i < 2; ++i) {
                uint2 v;
                v.x = packf(pre[i].x, pre[i].y);
                v.y = packf(pre[i].z, pre[i].w);
                *(uint2*)&xs[(p + 1) & 1][(chl + 16 * i) * XSTD + 2 * colq] = v;
            }
            __syncthreads();
        }
    }

    // ---- bias + relu + BN; h -> hs (wave-private cols, same-wave consumer)
#pragma unroll
    for (int of = 0; of < 4; ++of) {
#pragma unroll
        for (int r = 0; r < 4; ++r) {
            const int o = 16 * of + 4 * lg + r;
            float hv = fmaxf(acc[of][r] + b1[o], 0.f) * scb[o] + shb[o];
            hs[o * HSTH + colL] = hu16((__fp16)hv);
        }
    }

    // ---- Phase 2: kern = w2 . h  (7 r-frags x 2 K-steps) ----
    f32x4 acc2[7];
#pragma unroll
    for (int rf = 0; rf < 7; ++rf) acc2[rf] = (f32x4){0.f, 0.f, 0.f, 0.f};

#pragma unroll
    for (int kx = 0; kx < 2; ++kx) {
        half8 bf;
#pragma unroll
        for (int j = 0; j < 8; ++j)
            bf[j] = u16h(hs[(32 * kx + 8 * lg + j) * HSTH + colL]);
#pragma unroll
        for (int rf = 0; rf < 7; ++rf) {
            half8 af = *(const half8*)(w2f + (16 * rf + lr) * HID + 32 * kx + 8 * lg);
            acc2[rf] = __builtin_amdgcn_mfma_f32_16x16x32_f16(af, bf, acc2[rf], 0, 0, 0);
        }
    }

    // ---- bias + row-pair pack -> ks LDS
#pragma unroll
    for (int rf = 0; rf < 7; ++rf) {
#pragma unroll
        for (int p = 0; p < 2; ++p) {
            const int r0 = 16 * rf + 4 * lg + 2 * p;
            float k0 = acc2[rf][2 * p + 0] + b2[r0 + 0];
            float k1 = acc2[rf][2 * p + 1] + b2[r0 + 1];
            ks[(r0 >> 1) * KSTD + colL] = packf(k0, k1);
        }
    }
    __syncthreads();

    // ---- Involution: wave w -> groups {4w..4w+3}; x taps from global f32 ----
    const int q4   = lane & 15;
    const int hi   = lane >> 4;            // 0..3
    const int col0 = l0 + 4 * q4;

#pragma unroll
    for (int gi = 0; gi < 4; ++gi) {
        const int g   = 4 * w + gi;        // parity = gi & 1
        const int rpb = (7 * g) >> 1;
        uint4 qq[4];
#pragma unroll
        for (int ii = 0; ii < 4; ++ii)
            qq[ii] = *(const uint4*)(ks + (rpb + ii) * KSTD + 4 * q4);
        float kv[KK][4];
        if ((gi & 1) == 0) extract_kv<0>(qq, kv);
        else               extract_kv<1>(qq, kv);

#pragma unroll 4
        for (int i2 = 0; i2 < 4; ++i2) {
            const int ch = 16 * g + 4 * i2 + hi;
            const float* xrow = x + ((size_t)b * CHN + ch) * DIMN;
            float4 fa = *(const float4*)(xrow + (col0 > 0 ? col0 - 4 : 0));
            float4 fb = *(const float4*)(xrow + col0);
            float4 fc = *(const float4*)(xrow + (col0 + 4 < DIMN ? col0 + 4 : DIMN - 4));

            float xr[10] = { fa.y, fa.z, fa.w, fb.x, fb.y, fb.z, fb.w, fc.x, fc.y, fc.z };
            if (col0 == 0)        { xr[0] = 0.f; xr[1] = 0.f; xr[2] = 0.f; }
            if (col0 == DIMN - 4) { xr[7] = 0.f; xr[8] = 0.f; xr[9] = 0.f; }

            float o0 = 0.f, o1 = 0.f, o2 = 0.f, o3 = 0.f;
#pragma unroll
            for (int k = 0; k < KK; ++k) {
                o0 = fmaf(kv[k][0], xr[k + 0], o0);
                o1 = fmaf(kv[k][1], xr[k + 1], o1);
                o2 = fmaf(kv[k][2], xr[k + 2], o2);
                o3 = fmaf(kv[k][3], xr[k + 3], o3);
            }
            *(float4*)(out + ((size_t)b * CHN + ch) * DIMN + col0) =
                make_float4(o0, o1, o2, o3);
        }
    }
}

// ---------------------------------------------------------------------------
extern "C" void kernel_launch(void* const* d_in, const int* in_sizes, int n_in,
                              void* d_out, int out_size, void* d_ws, size_t ws_size,
                              hipStream_t stream) {
    (void)in_sizes; (void)n_in; (void)out_size; (void)ws_size;

    const float* x        = (const float*)d_in[0];
    const float* w1       = (const float*)d_in[1];
    const float* b1       = (const float*)d_in[2];
    const float* bn_gamma = (const float*)d_in[3];
    const float* bn_beta  = (const float*)d_in[4];
    const float* bn_mean  = (const float*)d_in[5];
    const float* bn_var   = (const float*)d_in[6];
    const float* w2       = (const float*)d_in[7];
    const float* b2       = (const float*)d_in[8];
    float*       out      = (float*)d_out;

    __fp16* w1f = (__fp16*)d_ws;                 // 16384 f16
    __fp16* w2f = w1f + HID * CHN;               // 7168 f16
    float*  scb = (float*)(w2f + KGN * HID);     // 64
    float*  shb = scb + HID;                     // 64

    setup_k<<<(HID * CHN + 255) / 256, 256, 0, stream>>>(
        w1, w2, bn_gamma, bn_beta, bn_mean, bn_var, w1f, w2f, scb, shb);
    fused_k<<<BB * (DIMN / TLC), 256, 0, stream>>>(
        x, w1f, b1, scb, shb, w2f, b2, out);
}

// Round 12
// 55.901 us; speedup vs baseline: 1.3649x; 1.0912x over previous
//
#include <hip/hip_runtime.h>

// Involution1d fused v5: B=16, CH=256, DIM=4096, G=16, K=7, PAD=3,
// hid=64, K*G=112.  setup (f16 weights) -> fused:
//   stage full x tile (f32->f16, +/-3 halo) into LDS with 1 barrier ->
//   MFMA kerngen (h wave-private, hs/ks overlaid union buffer) ->
//   involution with LDS f16 taps -> out.
// LDS 49.9 KiB -> 3 blocks/CU; x read once, out written once (~130 MB total).
#define BB   16
#define CHN  256
#define DIMN 4096
#define KK   7
#define PADK 3
#define HID  64
#define KGN  112
#define TLC  64        // columns (locations) per block tile
#define XSD  35        // xs row stride in dw (70 halves, odd dw -> conflict-free)
#define XSH  70        // xs row stride in halves
#define HSTH 70        // hs row stride in halves (35 dw)
#define KSTD 68        // ks row stride in dw (mult of 4 -> aligned uint4, conflict-free)
#define BN_EPS 1e-5f

typedef __fp16 half2_t __attribute__((ext_vector_type(2)));
typedef __fp16 half8   __attribute__((ext_vector_type(8)));
typedef float  f32x4   __attribute__((ext_vector_type(4)));

union U32H2 { unsigned int u; half2_t h; };

static __device__ __forceinline__ unsigned int packf(float a, float b) {
    U32H2 t; t.h = __builtin_amdgcn_cvt_pkrtz(a, b); return t.u;
}
static __device__ __forceinline__ half2_t ash2(unsigned int u) { U32H2 t; t.u = u; return t.h; }
static __device__ __forceinline__ __fp16 u16h(unsigned short u) {
    return __builtin_bit_cast(__fp16, u);
}
static __device__ __forceinline__ unsigned short hu16(__fp16 h) {
    return __builtin_bit_cast(unsigned short, h);
}

// ---------------------------------------------------------------------------
// Convert w1 [64][256] and w2 [112][64] to f16 (layout unchanged); BN affine.
__global__ __launch_bounds__(256) void setup_k(
    const float* __restrict__ w1, const float* __restrict__ w2,
    const float* __restrict__ bn_gamma, const float* __restrict__ bn_beta,
    const float* __restrict__ bn_mean,  const float* __restrict__ bn_var,
    __fp16* __restrict__ w1f, __fp16* __restrict__ w2f,
    float* __restrict__ scb, float* __restrict__ shb) {
    int t = blockIdx.x * 256 + threadIdx.x;   // grid covers 16384
    if (t < HID * CHN) w1f[t] = (__fp16)w1[t];
    if (t < KGN * HID) w2f[t] = (__fp16)w2[t];
    if (t < HID) {
        float s = bn_gamma[t] * rsqrtf(bn_var[t] + BN_EPS);
        scb[t] = s;
        shb[t] = bn_beta[t] - bn_mean[t] * s;
    }
}

// ---------------------------------------------------------------------------
// kern extraction from row-pair-packed uint4 quads; OFF = g&1.
template <int OFF>
static __device__ __forceinline__ void extract_kv(const uint4 q[4], float kv[KK][4]) {
#pragma unroll
    for (int k = 0; k < KK; ++k) {
        const int kk = k + OFF;
        const int i  = kk >> 1;
        const int h  = kk & 1;
#pragma unroll
        for (int j = 0; j < 4; ++j) {
            unsigned int u = (&q[i].x)[j];
            half2_t hh = ash2(u);
            kv[k][j] = h ? (float)hh[1] : (float)hh[0];
        }
    }
}

// ---------------------------------------------------------------------------
// Fused kernel.  Block = (b, 64-col tile), 4 waves, 3 blocks/CU.
// xs row layout (halves): [0..2] = left halo (cols l0-3..l0-1),
//   [3..66] = cols l0..l0+63 (hidx = col-l0+3), [67..69] = right halo.
// Phases 1/2: wave w owns cols [16w,16w+16) (colL).
// Involution: wave w owns g in {4w..4w+3}; lane -> col quad (l&15), ch (l>>4).
// Fragment maps (16x16x32): A[m][k]: m=lane&15, k=8*((lane>>4)&3)+j;
// B[k][n]: n=lane&15; D[m][n]: n=lane&15, m=4*((lane>>4)&3)+reg.
__global__ __launch_bounds__(256, 3) void fused_k(
    const float* __restrict__ x,
    const __fp16* __restrict__ w1f,
    const float* __restrict__ b1,
    const float* __restrict__ scb, const float* __restrict__ shb,
    const __fp16* __restrict__ w2f,
    const float* __restrict__ b2,
    float* __restrict__ out) {
    __shared__ unsigned int xs[CHN * XSD];   // 35840 B (f16 x tile + halo)
    __shared__ unsigned int un[56 * KSTD];   // 15232 B (hs then ks, overlaid)

    unsigned short* xs16 = (unsigned short*)xs;
    unsigned short* hs16 = (unsigned short*)un;
    unsigned int*   ks   = un;

    const int t    = threadIdx.x;          // 0..255
    const int lane = t & 63;
    const int w    = t >> 6;               // wave 0..3
    const int lr   = t & 15;
    const int lg   = (t >> 4) & 3;
    const int b    = blockIdx.x >> 6;
    const int l0   = (blockIdx.x & 63) * TLC;
    const int colL = 16 * w + lr;          // wave's column (0..63)

    // ---- Stage full x tile -> LDS f16 (one shot, 18 loads/thread) ----
    {
        const int colq = t & 15;           // col quad 0..15
        const int chl  = t >> 4;           // 0..15
        const float* xg = x + ((size_t)b * CHN + chl) * DIMN + l0 + 4 * colq;
        float4 v[16];
#pragma unroll
        for (int i = 0; i < 16; ++i)
            v[i] = *(const float4*)(xg + (size_t)(16 * i) * DIMN);
#pragma unroll
        for (int i = 0; i < 16; ++i) {
            unsigned short* rp = xs16 + (chl + 16 * i) * XSH + 4 * colq + 3;
            rp[0] = hu16((__fp16)v[i].x);
            *(unsigned int*)(rp + 1) = packf(v[i].y, v[i].z);
            rp[3] = hu16((__fp16)v[i].w);
        }
        // halo: thread t covers row t, both sides
        const float* xrow = x + ((size_t)b * CHN + t) * DIMN;
        float4 lv = (l0 > 0) ? *(const float4*)(xrow + l0 - 4)
                             : make_float4(0.f, 0.f, 0.f, 0.f);
        float4 rv = (l0 + TLC < DIMN) ? *(const float4*)(xrow + l0 + TLC)
                                      : make_float4(0.f, 0.f, 0.f, 0.f);
        unsigned short* hp = xs16 + t * XSH;
        hp[0]  = hu16((__fp16)lv.y);
        hp[1]  = hu16((__fp16)lv.z);
        hp[2]  = hu16((__fp16)lv.w);
        hp[67] = hu16((__fp16)rv.x);
        hp[68] = hu16((__fp16)rv.y);
        hp[69] = hu16((__fp16)rv.z);
    }
    __syncthreads();

    // ---- Phase 1: h = w1 . x  (4 o-frags x 8 K-steps) ----
    f32x4 acc[4];
#pragma unroll
    for (int of = 0; of < 4; ++of) acc[of] = (f32x4){0.f, 0.f, 0.f, 0.f};

#pragma unroll
    for (int p = 0; p < 8; ++p) {
        half8 bf;
#pragma unroll
        for (int j = 0; j < 8; ++j)
            bf[j] = u16h(xs16[(32 * p + 8 * lg + j) * XSH + colL + 3]);
#pragma unroll
        for (int of = 0; of < 4; ++of) {
            half8 af = *(const half8*)(w1f + (16 * of + lr) * CHN + 32 * p + 8 * lg);
            acc[of] = __builtin_amdgcn_mfma_f32_16x16x32_f16(af, bf, acc[of], 0, 0, 0);
        }
    }

    // ---- bias + relu + BN; h -> hs (wave-private cols, same-wave consumer)
#pragma unroll
    for (int of = 0; of < 4; ++of) {
#pragma unroll
        for (int r = 0; r < 4; ++r) {
            const int o = 16 * of + 4 * lg + r;
            float hv = fmaxf(acc[of][r] + b1[o], 0.f) * scb[o] + shb[o];
            hs16[o * HSTH + colL] = hu16((__fp16)hv);
        }
    }

    // ---- Phase 2: kern = w2 . h  (7 r-frags x 2 K-steps) ----
    f32x4 acc2[7];
#pragma unroll
    for (int rf = 0; rf < 7; ++rf) acc2[rf] = (f32x4){0.f, 0.f, 0.f, 0.f};

#pragma unroll
    for (int kx = 0; kx < 2; ++kx) {
        half8 bf;
#pragma unroll
        for (int j = 0; j < 8; ++j)
            bf[j] = u16h(hs16[(32 * kx + 8 * lg + j) * HSTH + colL]);
#pragma unroll
        for (int rf = 0; rf < 7; ++rf) {
            half8 af = *(const half8*)(w2f + (16 * rf + lr) * HID + 32 * kx + 8 * lg);
            acc2[rf] = __builtin_amdgcn_mfma_f32_16x16x32_f16(af, bf, acc2[rf], 0, 0, 0);
        }
    }

    // all hs reads done; barrier before overlaying ks onto the union buffer
    __syncthreads();

    // ---- bias + row-pair pack -> ks (overlaid on hs region)
#pragma unroll
    for (int rf = 0; rf < 7; ++rf) {
#pragma unroll
        for (int p = 0; p < 2; ++p) {
            const int r0 = 16 * rf + 4 * lg + 2 * p;
            float k0 = acc2[rf][2 * p + 0] + b2[r0 + 0];
            float k1 = acc2[rf][2 * p + 1] + b2[r0 + 1];
            ks[(r0 >> 1) * KSTD + colL] = packf(k0, k1);
        }
    }
    __syncthreads();

    // ---- Involution: wave w -> groups {4w..4w+3}; taps from LDS f16 ----
    const int q4    = lane & 15;
    const int hi    = lane >> 4;           // 0..3
    const int cbase = 4 * q4;              // relative col of this lane's quad

#pragma unroll
    for (int gi = 0; gi < 4; ++gi) {
        const int g   = 4 * w + gi;        // parity = g & 1 (w*4 even)
        const int rpb = (7 * g) >> 1;
        uint4 qq[4];
#pragma unroll
        for (int ii = 0; ii < 4; ++ii)
            qq[ii] = *(const uint4*)(ks + (rpb + ii) * KSTD + cbase);
        float kv[KK][4];
        if ((g & 1) == 0) extract_kv<0>(qq, kv);
        else              extract_kv<1>(qq, kv);

#pragma unroll
        for (int i2 = 0; i2 < 4; ++i2) {
            const int ch = 16 * g + 4 * i2 + hi;
            const unsigned int* xr = xs + ch * XSD + (cbase >> 1);
            unsigned int uu[5];
#pragma unroll
            for (int j = 0; j < 5; ++j) uu[j] = xr[j];
            // halves cbase..cbase+9 of this row; out col cc=cbase+j taps xv[j..j+6]
            float xv[10];
#pragma unroll
            for (int r = 0; r < 10; ++r) {
                half2_t hh = ash2(uu[r >> 1]);
                xv[r] = (r & 1) ? (float)hh[1] : (float)hh[0];
            }
            float o0 = 0.f, o1 = 0.f, o2 = 0.f, o3 = 0.f;
#pragma unroll
            for (int k = 0; k < KK; ++k) {
                o0 = fmaf(kv[k][0], xv[k + 0], o0);
                o1 = fmaf(kv[k][1], xv[k + 1], o1);
                o2 = fmaf(kv[k][2], xv[k + 2], o2);
                o3 = fmaf(kv[k][3], xv[k + 3], o3);
            }
            *(float4*)(out + ((size_t)b * CHN + ch) * DIMN + l0 + cbase) =
                make_float4(o0, o1, o2, o3);
        }
    }
}

// ---------------------------------------------------------------------------
extern "C" void kernel_launch(void* const* d_in, const int* in_sizes, int n_in,
                              void* d_out, int out_size, void* d_ws, size_t ws_size,
                              hipStream_t stream) {
    (void)in_sizes; (void)n_in; (void)out_size; (void)ws_size;

    const float* x        = (const float*)d_in[0];
    const float* w1       = (const float*)d_in[1];
    const float* b1       = (const float*)d_in[2];
    const float* bn_gamma = (const float*)d_in[3];
    const float* bn_beta  = (const float*)d_in[4];
    const float* bn_mean  = (const float*)d_in[5];
    const float* bn_var   = (const float*)d_in[6];
    const float* w2       = (const float*)d_in[7];
    const float* b2       = (const float*)d_in[8];
    float*       out      = (float*)d_out;

    __fp16* w1f = (__fp16*)d_ws;                 // 16384 f16
    __fp16* w2f = w1f + HID * CHN;               // 7168 f16
    float*  scb = (float*)(w2f + KGN * HID);     // 64
    float*  shb = scb + HID;                     // 64

    setup_k<<<(HID * CHN + 255) / 256, 256, 0, stream>>>(
        w1, w2, bn_gamma, bn_beta, bn_mean, bn_var, w1f, w2f, scb, shb);
    fused_k<<<BB * (DIMN / TLC), 256, 0, stream>>>(
        x, w1f, b1, scb, shb, w2f, b2, out);
}